// Round 1
// 347.128 us; speedup vs baseline: 1.0921x; 1.0921x over previous
//
#include <hip/hip_runtime.h>
#include <hip/hip_bf16.h>

#define SEQ    4096
#define SCALE  0.125f

typedef __attribute__((ext_vector_type(8))) short s8v;
typedef __attribute__((ext_vector_type(4))) float f4v;

__device__ __forceinline__ unsigned short f2bf(float f){
  unsigned int u = __builtin_bit_cast(unsigned int, f);
  u += 0x7FFFu + ((u >> 16) & 1u);
  return (unsigned short)(u >> 16);
}

typedef const __attribute__((address_space(1))) unsigned int gl_uint;
typedef __attribute__((address_space(3))) unsigned int lds_uint;

__device__ __forceinline__ void gload_lds16(const unsigned short* g, unsigned short* l){
  __builtin_amdgcn_global_load_lds((gl_uint*)g, (lds_uint*)l, 16, 0, 0);
}

#define MM(a,b,c) __builtin_amdgcn_mfma_f32_16x16x32_bf16(a,b,c,0,0,0)
#define BAR() __builtin_amdgcn_s_barrier()
#define LGKM0() do{ asm volatile("s_waitcnt lgkmcnt(0)" ::: "memory"); \
                    __builtin_amdgcn_sched_barrier(0); }while(0)
#define VMW(n) asm volatile("s_waitcnt vmcnt(" #n ")" ::: "memory")

// ---------------- shared 256x256-tile GEMM mainloop, K=1024, BK=32.
// 8 waves (2M x 4N), per-wave output 128x64 (acc[8][4] 16x16 frags).
// 4-deep LDS ring (4 x (A 16KB + B 16KB) = 128 KiB), one tile staged 3 ahead.
// LDS chunk swizzle: byte ^= ((byte>>8)&3)<<4  (involution, 16B-granular):
//   write side = pre-swizzled GLOBAL source (gload_lds dest stays linear),
//   read side  = swizzled ds_read address. 64-lane ds_read_b128 -> conflict-free.
// Per K-tile: phase A {read b0-3,a0-3; stage A(t+3); bar; lgkm0; 16 MFMA; bar}
//             phase B {read a4-7;      stage B(t+3); vmcnt(8); bar; lgkm0; 16 MFMA; bar}
__device__ __forceinline__ void mainloop_256(
    const unsigned short* __restrict__ Ag,
    const unsigned short* __restrict__ Bg,
    int bm, int bn, f4v (&acc)[8][4])
{
  __shared__ __align__(16) unsigned short lds[65536];   // 128 KiB
  const int tid  = threadIdx.x;
  const int wave = tid >> 6, lane = tid & 63;
  const int quad = lane >> 4, l16 = lane & 15;
  const int wmi  = wave >> 2, wni = wave & 3;

  // staging: thread t writes LDS bytes t*16 (+8192): row = t>>2 (+128),
  // content chunk = (t&3) ^ ((t>>4)&3)  (inverse of read swizzle)
  const int schunk = (((tid & 3) ^ ((tid >> 4) & 3)) * 8);
  const unsigned short* aS = Ag + (size_t)(bm + (tid >> 2)) * 1024 + schunk;
  const unsigned short* bS = Bg + (size_t)(bn + (tid >> 2)) * 1024 + schunk;
  unsigned short* ldsw = lds + wave * 512;   // wave-uniform gload_lds base

  int aoff[8], boff[4];
#pragma unroll
  for (int mf = 0; mf < 8; mf++){
    int r = wmi * 128 + mf * 16 + l16;
    aoff[mf] = r * 32 + ((quad ^ ((r >> 2) & 3)) * 8);
  }
#pragma unroll
  for (int nf = 0; nf < 4; nf++){
    int c = wni * 64 + nf * 16 + l16;
    boff[nf] = 8192 + c * 32 + ((quad ^ ((c >> 2) & 3)) * 8);
  }

#define STG_A(t_) do{ unsigned short* d_ = ldsw + ((t_) & 3) * 16384; \
    const unsigned short* s_ = aS + (t_) * 32; \
    gload_lds16(s_, d_); gload_lds16(s_ + 128 * 1024, d_ + 4096); }while(0)
#define STG_B(t_) do{ unsigned short* d_ = ldsw + ((t_) & 3) * 16384 + 8192; \
    const unsigned short* s_ = bS + (t_) * 32; \
    gload_lds16(s_, d_); gload_lds16(s_ + 128 * 1024, d_ + 4096); }while(0)

  // prologue: tiles 0,1,2 in flight; wait tile 0 (keep 8 = tiles 1,2 outstanding)
  STG_A(0); STG_B(0); STG_A(1); STG_B(1); STG_A(2); STG_B(2);
  VMW(8); BAR();

  s8v a0, a1, a2, a3, b0, b1, b2, b3;

#define PH_A(t_, STG) do{ \
    const unsigned short* base_ = lds + ((t_) & 3) * 16384; \
    b0 = *(const s8v*)(base_ + boff[0]); b1 = *(const s8v*)(base_ + boff[1]); \
    b2 = *(const s8v*)(base_ + boff[2]); b3 = *(const s8v*)(base_ + boff[3]); \
    a0 = *(const s8v*)(base_ + aoff[0]); a1 = *(const s8v*)(base_ + aoff[1]); \
    a2 = *(const s8v*)(base_ + aoff[2]); a3 = *(const s8v*)(base_ + aoff[3]); \
    if (STG) STG_A((t_) + 3); \
    BAR(); LGKM0(); \
    __builtin_amdgcn_s_setprio(1); \
    acc[0][0]=MM(a0,b0,acc[0][0]); acc[0][1]=MM(a0,b1,acc[0][1]); \
    acc[0][2]=MM(a0,b2,acc[0][2]); acc[0][3]=MM(a0,b3,acc[0][3]); \
    acc[1][0]=MM(a1,b0,acc[1][0]); acc[1][1]=MM(a1,b1,acc[1][1]); \
    acc[1][2]=MM(a1,b2,acc[1][2]); acc[1][3]=MM(a1,b3,acc[1][3]); \
    acc[2][0]=MM(a2,b0,acc[2][0]); acc[2][1]=MM(a2,b1,acc[2][1]); \
    acc[2][2]=MM(a2,b2,acc[2][2]); acc[2][3]=MM(a2,b3,acc[2][3]); \
    acc[3][0]=MM(a3,b0,acc[3][0]); acc[3][1]=MM(a3,b1,acc[3][1]); \
    acc[3][2]=MM(a3,b2,acc[3][2]); acc[3][3]=MM(a3,b3,acc[3][3]); \
    __builtin_amdgcn_s_setprio(0); \
    BAR(); }while(0)

#define PH_B(t_, STG, VN) do{ \
    const unsigned short* base_ = lds + ((t_) & 3) * 16384; \
    a0 = *(const s8v*)(base_ + aoff[4]); a1 = *(const s8v*)(base_ + aoff[5]); \
    a2 = *(const s8v*)(base_ + aoff[6]); a3 = *(const s8v*)(base_ + aoff[7]); \
    if (STG) STG_B((t_) + 3); \
    VMW(VN); \
    BAR(); LGKM0(); \
    __builtin_amdgcn_s_setprio(1); \
    acc[4][0]=MM(a0,b0,acc[4][0]); acc[4][1]=MM(a0,b1,acc[4][1]); \
    acc[4][2]=MM(a0,b2,acc[4][2]); acc[4][3]=MM(a0,b3,acc[4][3]); \
    acc[5][0]=MM(a1,b0,acc[5][0]); acc[5][1]=MM(a1,b1,acc[5][1]); \
    acc[5][2]=MM(a1,b2,acc[5][2]); acc[5][3]=MM(a1,b3,acc[5][3]); \
    acc[6][0]=MM(a2,b0,acc[6][0]); acc[6][1]=MM(a2,b1,acc[6][1]); \
    acc[6][2]=MM(a2,b2,acc[6][2]); acc[6][3]=MM(a2,b3,acc[6][3]); \
    acc[7][0]=MM(a3,b0,acc[7][0]); acc[7][1]=MM(a3,b1,acc[7][1]); \
    acc[7][2]=MM(a3,b2,acc[7][2]); acc[7][3]=MM(a3,b3,acc[7][3]); \
    __builtin_amdgcn_s_setprio(0); \
    BAR(); }while(0)

  // main loop: 32 K-tiles; counted vmcnt(8) = tiles t+2,t+3 allowed in flight
  for (int t = 0; t < 29; ++t){
    PH_A(t, 1);
    PH_B(t, 1, 8);
  }
  PH_A(29, 0); PH_B(29, 0, 4);   // ensure tile 30 ready (tile 31 outstanding)
  PH_A(30, 0); PH_B(30, 0, 0);   // drain: tile 31 ready
  PH_A(31, 0); PH_B(31, 0, 0);

#undef PH_A
#undef PH_B
#undef STG_A
#undef STG_B
}

// ---------------- qkv GEMM (fused q-softmax + k-exp), 256x256 tile
__global__ __launch_bounds__(512, 2) void qkv_gemm(
    const unsigned short* __restrict__ A,
    const unsigned short* __restrict__ Bt,
    unsigned short* __restrict__ qt,
    unsigned short* __restrict__ kt,
    unsigned short* __restrict__ vb)
{
  const int id  = blockIdx.x;
  const int swz = (id & 7) * 96 + (id >> 3);     // 768 blocks, bijective XCD swizzle
  const int bm  = (swz / 12) * 256, bn = (swz % 12) * 256;

  f4v acc[8][4];
#pragma unroll
  for (int i = 0; i < 8; i++)
#pragma unroll
    for (int j = 0; j < 4; j++) acc[i][j] = (f4v){0.f,0.f,0.f,0.f};

  mainloop_256(A, Bt, bm, bn, acc);

  const int tid = threadIdx.x;
  const int wave = tid >> 6, lane = tid & 63;
  const int quad = lane >> 4, l16 = lane & 15;
  const int wmi = wave >> 2, wni = wave & 3;
  const int colbase = bn + wni * 64;             // 64-aligned -> one head per wave
  const int rowbase = bm + wmi * 128;
  const int sec = colbase >> 10;                 // 0=q 1=k 2=v (wave-uniform)

  if (sec == 2){
#pragma unroll
    for (int nf = 0; nf < 4; nf++){
      int vc = colbase + nf * 16 + l16 - 2048;
#pragma unroll
      for (int mf = 0; mf < 8; mf++){
        int row = rowbase + mf * 16 + quad * 4;
#pragma unroll
        for (int r = 0; r < 4; r++)
          vb[(size_t)(row + r) * 1024 + vc] = f2bf(acc[mf][nf][r]);
      }
    }
    return;
  }

  if (sec == 0){
    // fused softmax over d (wave's 64 cols = full head)
#pragma unroll
    for (int mf = 0; mf < 8; mf++){
#pragma unroll
      for (int r = 0; r < 4; r++){
        float m = fmaxf(fmaxf(acc[mf][0][r], acc[mf][1][r]),
                        fmaxf(acc[mf][2][r], acc[mf][3][r]));
        for (int off = 8; off; off >>= 1) m = fmaxf(m, __shfl_xor(m, off));
        m *= SCALE;
        float e0 = __expf(acc[mf][0][r] * SCALE - m);
        float e1 = __expf(acc[mf][1][r] * SCALE - m);
        float e2 = __expf(acc[mf][2][r] * SCALE - m);
        float e3 = __expf(acc[mf][3][r] * SCALE - m);
        float s = (e0 + e1) + (e2 + e3);
        for (int off = 8; off; off >>= 1) s += __shfl_xor(s, off);
        float inv = 1.f / s;
        acc[mf][0][r] = e0 * inv; acc[mf][1][r] = e1 * inv;
        acc[mf][2][r] = e2 * inv; acc[mf][3][r] = e3 * inv;
      }
    }
#pragma unroll
    for (int nf = 0; nf < 4; nf++){
      int col = colbase + nf * 16 + l16;
      int h = (col >> 6) & 15, de = col & 63;
#pragma unroll
      for (int mf = 0; mf < 8; mf++){
        int row = rowbase + mf * 16 + quad * 4;
        int bb = row >> 12, nl = row & 4095;
        ushort4 o;
        o.x = f2bf(acc[mf][nf][0]); o.y = f2bf(acc[mf][nf][1]);
        o.z = f2bf(acc[mf][nf][2]); o.w = f2bf(acc[mf][nf][3]);
        *(ushort4*)&qt[(((size_t)bb * 16 + h) * 64 + de) * SEQ + nl] = o;
      }
    }
  } else {
    // k: exp per element; normalizer recovered in ctx2 (q cols sum to 1)
#pragma unroll
    for (int nf = 0; nf < 4; nf++){
      int col = colbase + nf * 16 + l16;
      int h = (col >> 6) & 15, de = col & 63;
#pragma unroll
      for (int mf = 0; mf < 8; mf++){
        int row = rowbase + mf * 16 + quad * 4;
        int bb = row >> 12, nl = row & 4095;
        ushort4 o;
        o.x = f2bf(__expf(acc[mf][nf][0])); o.y = f2bf(__expf(acc[mf][nf][1]));
        o.z = f2bf(__expf(acc[mf][nf][2])); o.w = f2bf(__expf(acc[mf][nf][3]));
        *(ushort4*)&kt[(((size_t)bb * 16 + h) * 64 + de) * SEQ + nl] = o;
      }
    }
  }
}

// ---------------- final batched GEMM: out[b] = vb[b] @ ctx2t[b]^T + bias, fp32
__global__ __launch_bounds__(512, 2) void gemm_final(
    const unsigned short* __restrict__ A,
    const unsigned short* __restrict__ C2t,
    float* __restrict__ Cf,
    const float* __restrict__ bias)
{
  const int id  = blockIdx.x;
  const int swz = (id & 7) * 32 + (id >> 3);     // 256 blocks, bijective XCD swizzle
  const int bm  = (swz >> 2) * 256, bn = (swz & 3) * 256;
  const unsigned short* Bt = C2t + (size_t)(bm >> 12) * 1024 * 1024;

  f4v acc[8][4];
#pragma unroll
  for (int i = 0; i < 8; i++)
#pragma unroll
    for (int j = 0; j < 4; j++) acc[i][j] = (f4v){0.f,0.f,0.f,0.f};

  mainloop_256(A, Bt, bm, bn, acc);

  const int tid = threadIdx.x;
  const int wave = tid >> 6, lane = tid & 63;
  const int quad = lane >> 4, l16 = lane & 15;
  const int wmi = wave >> 2, wni = wave & 3;

#pragma unroll
  for (int nf = 0; nf < 4; nf++){
    int col = bn + wni * 64 + nf * 16 + l16;
    float bv = bias[col];
#pragma unroll
    for (int mf = 0; mf < 8; mf++){
      int row = bm + wmi * 128 + mf * 16 + quad * 4;
#pragma unroll
      for (int r = 0; r < 4; r++)
        Cf[(size_t)(row + r) * 1024 + col] = acc[mf][nf][r] + bv;
    }
  }
}

// ---------------- fp32 -> bf16 elementwise (4/thread)
__global__ void cvt_f32_bf16(const float4* __restrict__ in, ushort4* __restrict__ outp){
  int i = blockIdx.x * 256 + threadIdx.x;
  float4 v = in[i];
  ushort4 o;
  o.x = f2bf(v.x); o.y = f2bf(v.y); o.z = f2bf(v.z); o.w = f2bf(v.w);
  outp[i] = o;
}

// ---------------- transpose + cvt: in[R,C] fp32 -> out[C,R] bf16
__global__ __launch_bounds__(256) void transpose_cvt(const float* __restrict__ in,
                                                     unsigned short* __restrict__ outp,
                                                     int R, int C){
  __shared__ float tile[64][65];
  int r0 = blockIdx.y * 64, c0 = blockIdx.x * 64;
  int t = threadIdx.x;
  for (int i = t; i < 4096; i += 256){ int r = i >> 6, c = i & 63;
    tile[r][c] = in[(size_t)(r0 + r) * C + c0 + c]; }
  __syncthreads();
  for (int i = t; i < 4096; i += 256){ int c = i >> 6, r = i & 63;
    outp[(size_t)(c0 + c) * R + r0 + r] = f2bf(tile[r][c]); }
}

// ---------------- ctx partial: ctxp[bh*4+chunk][d*64+e] = sum_{n in chunk} qt[d,n] kt[e,n]
__global__ __launch_bounds__(256) void ctx_partial(const unsigned short* __restrict__ qt,
                                                   const unsigned short* __restrict__ kt,
                                                   float* __restrict__ ctxp){
  __shared__ float red[4096];
  int bh = blockIdx.x >> 2, ch = blockIdx.x & 3;
  int t = threadIdx.x, wave = t >> 6, lane = t & 63, quad = lane >> 4, l16 = lane & 15;
  const unsigned short* qb = qt + (size_t)bh * 64 * SEQ;
  const unsigned short* kb = kt + (size_t)bh * 64 * SEQ;
  f4v acc[4][4];
#pragma unroll
  for (int i = 0; i < 4; i++)
#pragma unroll
    for (int j = 0; j < 4; j++) acc[i][j] = (f4v){0.f,0.f,0.f,0.f};
  int ns = ch * 1024 + wave * 256;
  for (int n0 = ns; n0 < ns + 256; n0 += 32){
    s8v af[4], bf[4];
#pragma unroll
    for (int mt = 0; mt < 4; mt++) af[mt] = *(const s8v*)&qb[(size_t)(mt*16 + l16) * SEQ + n0 + quad*8];
#pragma unroll
    for (int nt = 0; nt < 4; nt++) bf[nt] = *(const s8v*)&kb[(size_t)(nt*16 + l16) * SEQ + n0 + quad*8];
#pragma unroll
    for (int mt = 0; mt < 4; mt++)
#pragma unroll
      for (int nt = 0; nt < 4; nt++)
        acc[mt][nt] = __builtin_amdgcn_mfma_f32_16x16x32_bf16(af[mt], bf[nt], acc[mt][nt], 0, 0, 0);
  }
  for (int i = t; i < 4096; i += 256) red[i] = 0.f;
  __syncthreads();
  for (int w = 0; w < 4; w++){
    if (wave == w){
#pragma unroll
      for (int mt = 0; mt < 4; mt++)
#pragma unroll
        for (int nt = 0; nt < 4; nt++)
#pragma unroll
          for (int r = 0; r < 4; r++)
            red[(mt*16 + quad*4 + r) * 64 + nt*16 + l16] += acc[mt][nt][r];
    }
    __syncthreads();
  }
  float* cp = ctxp + (size_t)blockIdx.x * 4096;
  for (int i = t; i < 4096; i += 256) cp[i] = red[i];
}

// ---------------- ctx2t[b][f][h*64+d] = sum_e ctx[d][e]*inv[e] * w_out[h*64+e][f]  (bf16 out)
__global__ __launch_bounds__(256) void ctx2_kernel(const float* __restrict__ ctxp,
                                                   const float* __restrict__ w_out,
                                                   unsigned short* __restrict__ ctx2t){
  __shared__ float ctxs[4096];
  __shared__ float inv_s[64];
  int bh = blockIdx.x >> 4, fc = blockIdx.x & 15;
  int b = bh >> 4, h = bh & 15;
  int t = threadIdx.x;
  int fl = t & 63, dg = t >> 6;
  int f = fc * 64 + fl;
  for (int i = t; i < 4096; i += 256){
    const float* p = ctxp + (size_t)bh * 4 * 4096 + i;
    ctxs[i] = (p[0] + p[4096]) + (p[8192] + p[12288]);
  }
  __syncthreads();
  if (t < 64){
    float s = 0.f;
#pragma unroll
    for (int d = 0; d < 64; d++) s += ctxs[d * 64 + t];
    inv_s[t] = 1.f / s;
  }
  __syncthreads();
  float acc[16];
#pragma unroll
  for (int i = 0; i < 16; i++) acc[i] = 0.f;
  for (int e = 0; e < 64; e++){
    float w = w_out[(size_t)(h * 64 + e) * 1024 + f] * inv_s[e];
#pragma unroll
    for (int dd = 0; dd < 16; dd++)
      acc[dd] += ctxs[(dg * 16 + dd) * 64 + e] * w;
  }
  unsigned short* op = ctx2t + ((size_t)b * 1024 + f) * 1024 + h * 64 + dg * 16;
#pragma unroll
  for (int g = 0; g < 4; g++){
    ushort4 o;
    o.x = f2bf(acc[g*4+0]); o.y = f2bf(acc[g*4+1]);
    o.z = f2bf(acc[g*4+2]); o.w = f2bf(acc[g*4+3]);
    *(ushort4*)&op[g*4] = o;
  }
}

extern "C" void kernel_launch(void* const* d_in, const int* in_sizes, int n_in,
                              void* d_out, int out_size, void* d_ws, size_t ws_size,
                              hipStream_t stream) {
  const float* x     = (const float*)d_in[0];  // [4,4096,1024]
  const float* w_qkv = (const float*)d_in[1];  // [1024,3072]
  const float* w_out = (const float*)d_in[2];  // [1024,1024]
  const float* b_out = (const float*)d_in[3];  // [1024]
  float* out = (float*)d_out;                  // [4,4096,1024] fp32

  const int M = 4 * SEQ;  // 16384

  unsigned short* xb = (unsigned short*)d_out;  // dead before gemm_final writes

  char* wp = (char*)d_ws;
  size_t off = 0;
  auto nxt = [&](size_t bytes) -> char* {
    char* p = wp + off;
    off += (bytes + 255) & ~(size_t)255;
    return p;
  };
  unsigned short* wqkvT = (unsigned short*)nxt((size_t)3072 * 1024 * 2);
  unsigned short* qt    = (unsigned short*)nxt((size_t)64 * 64 * SEQ * 2);
  unsigned short* kt    = (unsigned short*)nxt((size_t)64 * 64 * SEQ * 2);
  unsigned short* vb    = (unsigned short*)nxt((size_t)M * 1024 * 2);
  float*          ctxp  = (float*)wqkvT;       // aliases wqkvT (dead after qkv_gemm)
  unsigned short* ctx2t = qt;                  // aliases qt (dead after ctx_partial)

  // 1. converts
  cvt_f32_bf16<<<(M * 1024) / 4 / 256, 256, 0, stream>>>((const float4*)x, (ushort4*)xb);
  transpose_cvt<<<dim3(3072 / 64, 1024 / 64), 256, 0, stream>>>(w_qkv, wqkvT, 1024, 3072);

  // 2. fused qkv GEMM (256^2 tile, 4-deep pipeline) -> qt, kt, vb
  qkv_gemm<<<768, 512, 0, stream>>>(xb, wqkvT, qt, kt, vb);

  // 3. context partials (fp32), 256 blocks
  ctx_partial<<<64 * 4, 256, 0, stream>>>(qt, kt, ctxp);

  // 4. ctx2t[b][f][hd]
  ctx2_kernel<<<64 * 16, 256, 0, stream>>>(ctxp, w_out, ctx2t);

  // 5. final batched GEMM (256^2 tile, 4-deep pipeline)
  gemm_final<<<256, 512, 0, stream>>>(vb, ctx2t, out, b_out);
}

// Round 4
// 343.935 us; speedup vs baseline: 1.1022x; 1.0093x over previous
//
#include <hip/hip_runtime.h>
#include <hip/hip_bf16.h>

#define SEQ    4096
#define SCALE  0.125f

typedef __attribute__((ext_vector_type(8))) short s8v;
typedef __attribute__((ext_vector_type(4))) float f4v;

__device__ __forceinline__ unsigned short f2bf(float f){
  unsigned int u = __builtin_bit_cast(unsigned int, f);
  u += 0x7FFFu + ((u >> 16) & 1u);
  return (unsigned short)(u >> 16);
}

typedef const __attribute__((address_space(1))) unsigned int gl_uint;
typedef __attribute__((address_space(3))) unsigned int lds_uint;

__device__ __forceinline__ void gload_lds16(const unsigned short* g, unsigned short* l){
  __builtin_amdgcn_global_load_lds((gl_uint*)g, (lds_uint*)l, 16, 0, 0);
}

#define MM(a,b,c) __builtin_amdgcn_mfma_f32_16x16x32_bf16(a,b,c,0,0,0)
#define BAR() __builtin_amdgcn_s_barrier()
#define LGKM0() do{ asm volatile("s_waitcnt lgkmcnt(0)" ::: "memory"); \
                    __builtin_amdgcn_sched_barrier(0); }while(0)
#define VMW(n) asm volatile("s_waitcnt vmcnt(" #n ")" ::: "memory")

// ---------------- shared 256x256-tile GEMM mainloop, K=1024, BK=32.
// IDENTICAL structure to the round-1 verified kernel (8 waves 2Mx4N, 4-deep
// LDS ring = 128 KiB, PH_A/PH_B per K-tile, counted vmcnt(8)).
// ONLY change vs round-1: the LDS chunk swizzle is corrected from
//   chunk = quad ^ ((r>>2)&3)   (2-way residual conflict: slots {0,4,0,4,1,5,1,5})
// to
//   chunk = quad ^ ((r>>1)&3)   (conflict-free: an 8-lane b128 group covers
//                                slots {0,4,1,5,2,6,3,7} of its 128B window)
// Staging inverse accordingly: thread t fetches global chunk (t&3)^((t>>3)&3)
// (row = t>>2; second 8KB half starts at row 128 === 0 mod 8 -> same formula).
__device__ __forceinline__ void mainloop_256(
    const unsigned short* __restrict__ Ag,
    const unsigned short* __restrict__ Bg,
    int bm, int bn, f4v (&acc)[8][4])
{
  __shared__ __align__(16) unsigned short lds[65536];   // 128 KiB
  const int tid  = threadIdx.x;
  const int wave = tid >> 6, lane = tid & 63;
  const int quad = lane >> 4, l16 = lane & 15;
  const int wmi  = wave >> 2, wni = wave & 3;

  // staging: thread t writes LDS bytes t*16 (+8192): row = t>>2,
  // content chunk = (t&3) ^ ((t>>3)&3)  (inverse of read swizzle)
  const int schunk = (((tid & 3) ^ ((tid >> 3) & 3)) * 8);
  const unsigned short* aS = Ag + (size_t)(bm + (tid >> 2)) * 1024 + schunk;
  const unsigned short* bS = Bg + (size_t)(bn + (tid >> 2)) * 1024 + schunk;
  unsigned short* ldsw = lds + wave * 512;   // wave-uniform gload_lds base

  int aoff[8], boff[4];
#pragma unroll
  for (int mf = 0; mf < 8; mf++){
    int r = wmi * 128 + mf * 16 + l16;
    aoff[mf] = r * 32 + ((quad ^ ((r >> 1) & 3)) * 8);
  }
#pragma unroll
  for (int nf = 0; nf < 4; nf++){
    int c = wni * 64 + nf * 16 + l16;
    boff[nf] = 8192 + c * 32 + ((quad ^ ((c >> 1) & 3)) * 8);
  }

#define STG_A(t_) do{ unsigned short* d_ = ldsw + ((t_) & 3) * 16384; \
    const unsigned short* s_ = aS + (t_) * 32; \
    gload_lds16(s_, d_); gload_lds16(s_ + 128 * 1024, d_ + 4096); }while(0)
#define STG_B(t_) do{ unsigned short* d_ = ldsw + ((t_) & 3) * 16384 + 8192; \
    const unsigned short* s_ = bS + (t_) * 32; \
    gload_lds16(s_, d_); gload_lds16(s_ + 128 * 1024, d_ + 4096); }while(0)

  // prologue: tiles 0,1,2 in flight; wait tile 0 (keep 8 = tiles 1,2 outstanding)
  STG_A(0); STG_B(0); STG_A(1); STG_B(1); STG_A(2); STG_B(2);
  VMW(8); BAR();

  s8v a0, a1, a2, a3, b0, b1, b2, b3;

#define PH_A(t_, STG) do{ \
    const unsigned short* base_ = lds + ((t_) & 3) * 16384; \
    b0 = *(const s8v*)(base_ + boff[0]); b1 = *(const s8v*)(base_ + boff[1]); \
    b2 = *(const s8v*)(base_ + boff[2]); b3 = *(const s8v*)(base_ + boff[3]); \
    a0 = *(const s8v*)(base_ + aoff[0]); a1 = *(const s8v*)(base_ + aoff[1]); \
    a2 = *(const s8v*)(base_ + aoff[2]); a3 = *(const s8v*)(base_ + aoff[3]); \
    if (STG) STG_A((t_) + 3); \
    BAR(); LGKM0(); \
    __builtin_amdgcn_s_setprio(1); \
    acc[0][0]=MM(a0,b0,acc[0][0]); acc[0][1]=MM(a0,b1,acc[0][1]); \
    acc[0][2]=MM(a0,b2,acc[0][2]); acc[0][3]=MM(a0,b3,acc[0][3]); \
    acc[1][0]=MM(a1,b0,acc[1][0]); acc[1][1]=MM(a1,b1,acc[1][1]); \
    acc[1][2]=MM(a1,b2,acc[1][2]); acc[1][3]=MM(a1,b3,acc[1][3]); \
    acc[2][0]=MM(a2,b0,acc[2][0]); acc[2][1]=MM(a2,b1,acc[2][1]); \
    acc[2][2]=MM(a2,b2,acc[2][2]); acc[2][3]=MM(a2,b3,acc[2][3]); \
    acc[3][0]=MM(a3,b0,acc[3][0]); acc[3][1]=MM(a3,b1,acc[3][1]); \
    acc[3][2]=MM(a3,b2,acc[3][2]); acc[3][3]=MM(a3,b3,acc[3][3]); \
    __builtin_amdgcn_s_setprio(0); \
    BAR(); }while(0)

#define PH_B(t_, STG, VN) do{ \
    const unsigned short* base_ = lds + ((t_) & 3) * 16384; \
    a0 = *(const s8v*)(base_ + aoff[4]); a1 = *(const s8v*)(base_ + aoff[5]); \
    a2 = *(const s8v*)(base_ + aoff[6]); a3 = *(const s8v*)(base_ + aoff[7]); \
    if (STG) STG_B((t_) + 3); \
    VMW(VN); \
    BAR(); LGKM0(); \
    __builtin_amdgcn_s_setprio(1); \
    acc[4][0]=MM(a0,b0,acc[4][0]); acc[4][1]=MM(a0,b1,acc[4][1]); \
    acc[4][2]=MM(a0,b2,acc[4][2]); acc[4][3]=MM(a0,b3,acc[4][3]); \
    acc[5][0]=MM(a1,b0,acc[5][0]); acc[5][1]=MM(a1,b1,acc[5][1]); \
    acc[5][2]=MM(a1,b2,acc[5][2]); acc[5][3]=MM(a1,b3,acc[5][3]); \
    acc[6][0]=MM(a2,b0,acc[6][0]); acc[6][1]=MM(a2,b1,acc[6][1]); \
    acc[6][2]=MM(a2,b2,acc[6][2]); acc[6][3]=MM(a2,b3,acc[6][3]); \
    acc[7][0]=MM(a3,b0,acc[7][0]); acc[7][1]=MM(a3,b1,acc[7][1]); \
    acc[7][2]=MM(a3,b2,acc[7][2]); acc[7][3]=MM(a3,b3,acc[7][3]); \
    __builtin_amdgcn_s_setprio(0); \
    BAR(); }while(0)

  // main loop: 32 K-tiles; counted vmcnt(8) = tiles t+2,t+3 allowed in flight
  for (int t = 0; t < 29; ++t){
    PH_A(t, 1);
    PH_B(t, 1, 8);
  }
  PH_A(29, 0); PH_B(29, 0, 4);   // ensure tile 30 ready (tile 31 outstanding)
  PH_A(30, 0); PH_B(30, 0, 0);   // drain: tile 31 ready
  PH_A(31, 0); PH_B(31, 0, 0);

#undef PH_A
#undef PH_B
#undef STG_A
#undef STG_B
}

// ---------------- qkv GEMM (fused q-softmax + k-exp), 256x256 tile
__global__ __launch_bounds__(512, 2) void qkv_gemm(
    const unsigned short* __restrict__ A,
    const unsigned short* __restrict__ Bt,
    unsigned short* __restrict__ qt,
    unsigned short* __restrict__ kt,
    unsigned short* __restrict__ vb)
{
  const int id  = blockIdx.x;
  const int swz = (id & 7) * 96 + (id >> 3);     // 768 blocks, bijective XCD swizzle
  const int bm  = (swz / 12) * 256, bn = (swz % 12) * 256;

  f4v acc[8][4];
#pragma unroll
  for (int i = 0; i < 8; i++)
#pragma unroll
    for (int j = 0; j < 4; j++) acc[i][j] = (f4v){0.f,0.f,0.f,0.f};

  mainloop_256(A, Bt, bm, bn, acc);

  const int tid = threadIdx.x;
  const int wave = tid >> 6, lane = tid & 63;
  const int quad = lane >> 4, l16 = lane & 15;
  const int wmi = wave >> 2, wni = wave & 3;
  const int colbase = bn + wni * 64;             // 64-aligned -> one head per wave
  const int rowbase = bm + wmi * 128;
  const int sec = colbase >> 10;                 // 0=q 1=k 2=v (wave-uniform)

  if (sec == 2){
#pragma unroll
    for (int nf = 0; nf < 4; nf++){
      int vc = colbase + nf * 16 + l16 - 2048;
#pragma unroll
      for (int mf = 0; mf < 8; mf++){
        int row = rowbase + mf * 16 + quad * 4;
#pragma unroll
        for (int r = 0; r < 4; r++)
          vb[(size_t)(row + r) * 1024 + vc] = f2bf(acc[mf][nf][r]);
      }
    }
    return;
  }

  if (sec == 0){
    // fused softmax over d (wave's 64 cols = full head)
#pragma unroll
    for (int mf = 0; mf < 8; mf++){
#pragma unroll
      for (int r = 0; r < 4; r++){
        float m = fmaxf(fmaxf(acc[mf][0][r], acc[mf][1][r]),
                        fmaxf(acc[mf][2][r], acc[mf][3][r]));
        for (int off = 8; off; off >>= 1) m = fmaxf(m, __shfl_xor(m, off));
        m *= SCALE;
        float e0 = __expf(acc[mf][0][r] * SCALE - m);
        float e1 = __expf(acc[mf][1][r] * SCALE - m);
        float e2 = __expf(acc[mf][2][r] * SCALE - m);
        float e3 = __expf(acc[mf][3][r] * SCALE - m);
        float s = (e0 + e1) + (e2 + e3);
        for (int off = 8; off; off >>= 1) s += __shfl_xor(s, off);
        float inv = 1.f / s;
        acc[mf][0][r] = e0 * inv; acc[mf][1][r] = e1 * inv;
        acc[mf][2][r] = e2 * inv; acc[mf][3][r] = e3 * inv;
      }
    }
#pragma unroll
    for (int nf = 0; nf < 4; nf++){
      int col = colbase + nf * 16 + l16;
      int h = (col >> 6) & 15, de = col & 63;
#pragma unroll
      for (int mf = 0; mf < 8; mf++){
        int row = rowbase + mf * 16 + quad * 4;
        int bb = row >> 12, nl = row & 4095;
        ushort4 o;
        o.x = f2bf(acc[mf][nf][0]); o.y = f2bf(acc[mf][nf][1]);
        o.z = f2bf(acc[mf][nf][2]); o.w = f2bf(acc[mf][nf][3]);
        *(ushort4*)&qt[(((size_t)bb * 16 + h) * 64 + de) * SEQ + nl] = o;
      }
    }
  } else {
    // k: exp per element; normalizer recovered in ctx2 (q cols sum to 1)
#pragma unroll
    for (int nf = 0; nf < 4; nf++){
      int col = colbase + nf * 16 + l16;
      int h = (col >> 6) & 15, de = col & 63;
#pragma unroll
      for (int mf = 0; mf < 8; mf++){
        int row = rowbase + mf * 16 + quad * 4;
        int bb = row >> 12, nl = row & 4095;
        ushort4 o;
        o.x = f2bf(__expf(acc[mf][nf][0])); o.y = f2bf(__expf(acc[mf][nf][1]));
        o.z = f2bf(__expf(acc[mf][nf][2])); o.w = f2bf(__expf(acc[mf][nf][3]));
        *(ushort4*)&kt[(((size_t)bb * 16 + h) * 64 + de) * SEQ + nl] = o;
      }
    }
  }
}

// ---------------- final batched GEMM: out[b] = vb[b] @ ctx2t[b]^T + bias, fp32
__global__ __launch_bounds__(512, 2) void gemm_final(
    const unsigned short* __restrict__ A,
    const unsigned short* __restrict__ C2t,
    float* __restrict__ Cf,
    const float* __restrict__ bias)
{
  const int id  = blockIdx.x;
  const int swz = (id & 7) * 32 + (id >> 3);     // 256 blocks, bijective XCD swizzle
  const int bm  = (swz >> 2) * 256, bn = (swz & 3) * 256;
  const unsigned short* Bt = C2t + (size_t)(bm >> 12) * 1024 * 1024;

  f4v acc[8][4];
#pragma unroll
  for (int i = 0; i < 8; i++)
#pragma unroll
    for (int j = 0; j < 4; j++) acc[i][j] = (f4v){0.f,0.f,0.f,0.f};

  mainloop_256(A, Bt, bm, bn, acc);

  const int tid = threadIdx.x;
  const int wave = tid >> 6, lane = tid & 63;
  const int quad = lane >> 4, l16 = lane & 15;
  const int wmi = wave >> 2, wni = wave & 3;

#pragma unroll
  for (int nf = 0; nf < 4; nf++){
    int col = bn + wni * 64 + nf * 16 + l16;
    float bv = bias[col];
#pragma unroll
    for (int mf = 0; mf < 8; mf++){
      int row = bm + wmi * 128 + mf * 16 + quad * 4;
#pragma unroll
      for (int r = 0; r < 4; r++)
        Cf[(size_t)(row + r) * 1024 + col] = acc[mf][nf][r] + bv;
    }
  }
}

// ---------------- fp32 -> bf16 elementwise (4/thread)
__global__ void cvt_f32_bf16(const float4* __restrict__ in, ushort4* __restrict__ outp){
  int i = blockIdx.x * 256 + threadIdx.x;
  float4 v = in[i];
  ushort4 o;
  o.x = f2bf(v.x); o.y = f2bf(v.y); o.z = f2bf(v.z); o.w = f2bf(v.w);
  outp[i] = o;
}

// ---------------- transpose + cvt: in[R,C] fp32 -> out[C,R] bf16
__global__ __launch_bounds__(256) void transpose_cvt(const float* __restrict__ in,
                                                     unsigned short* __restrict__ outp,
                                                     int R, int C){
  __shared__ float tile[64][65];
  int r0 = blockIdx.y * 64, c0 = blockIdx.x * 64;
  int t = threadIdx.x;
  for (int i = t; i < 4096; i += 256){ int r = i >> 6, c = i & 63;
    tile[r][c] = in[(size_t)(r0 + r) * C + c0 + c]; }
  __syncthreads();
  for (int i = t; i < 4096; i += 256){ int c = i >> 6, r = i & 63;
    outp[(size_t)(c0 + c) * R + r0 + r] = f2bf(tile[r][c]); }
}

// ---------------- ctx partial: ctxp[bh*4+chunk][d*64+e] = sum_{n in chunk} qt[d,n] kt[e,n]
__global__ __launch_bounds__(256) void ctx_partial(const unsigned short* __restrict__ qt,
                                                   const unsigned short* __restrict__ kt,
                                                   float* __restrict__ ctxp){
  __shared__ float red[4096];
  int bh = blockIdx.x >> 2, ch = blockIdx.x & 3;
  int t = threadIdx.x, wave = t >> 6, lane = t & 63, quad = lane >> 4, l16 = lane & 15;
  const unsigned short* qb = qt + (size_t)bh * 64 * SEQ;
  const unsigned short* kb = kt + (size_t)bh * 64 * SEQ;
  f4v acc[4][4];
#pragma unroll
  for (int i = 0; i < 4; i++)
#pragma unroll
    for (int j = 0; j < 4; j++) acc[i][j] = (f4v){0.f,0.f,0.f,0.f};
  int ns = ch * 1024 + wave * 256;
  for (int n0 = ns; n0 < ns + 256; n0 += 32){
    s8v af[4], bf[4];
#pragma unroll
    for (int mt = 0; mt < 4; mt++) af[mt] = *(const s8v*)&qb[(size_t)(mt*16 + l16) * SEQ + n0 + quad*8];
#pragma unroll
    for (int nt = 0; nt < 4; nt++) bf[nt] = *(const s8v*)&kb[(size_t)(nt*16 + l16) * SEQ + n0 + quad*8];
#pragma unroll
    for (int mt = 0; mt < 4; mt++)
#pragma unroll
      for (int nt = 0; nt < 4; nt++)
        acc[mt][nt] = __builtin_amdgcn_mfma_f32_16x16x32_bf16(af[mt], bf[nt], acc[mt][nt], 0, 0, 0);
  }
  for (int i = t; i < 4096; i += 256) red[i] = 0.f;
  __syncthreads();
  for (int w = 0; w < 4; w++){
    if (wave == w){
#pragma unroll
      for (int mt = 0; mt < 4; mt++)
#pragma unroll
        for (int nt = 0; nt < 4; nt++)
#pragma unroll
          for (int r = 0; r < 4; r++)
            red[(mt*16 + quad*4 + r) * 64 + nt*16 + l16] += acc[mt][nt][r];
    }
    __syncthreads();
  }
  float* cp = ctxp + (size_t)blockIdx.x * 4096;
  for (int i = t; i < 4096; i += 256) cp[i] = red[i];
}

// ---------------- ctx2t[b][f][h*64+d] = sum_e ctx[d][e]*inv[e] * w_out[h*64+e][f]  (bf16 out)
__global__ __launch_bounds__(256) void ctx2_kernel(const float* __restrict__ ctxp,
                                                   const float* __restrict__ w_out,
                                                   unsigned short* __restrict__ ctx2t){
  __shared__ float ctxs[4096];
  __shared__ float inv_s[64];
  int bh = blockIdx.x >> 4, fc = blockIdx.x & 15;
  int b = bh >> 4, h = bh & 15;
  int t = threadIdx.x;
  int fl = t & 63, dg = t >> 6;
  int f = fc * 64 + fl;
  for (int i = t; i < 4096; i += 256){
    const float* p = ctxp + (size_t)bh * 4 * 4096 + i;
    ctxs[i] = (p[0] + p[4096]) + (p[8192] + p[12288]);
  }
  __syncthreads();
  if (t < 64){
    float s = 0.f;
#pragma unroll
    for (int d = 0; d < 64; d++) s += ctxs[d * 64 + t];
    inv_s[t] = 1.f / s;
  }
  __syncthreads();
  float acc[16];
#pragma unroll
  for (int i = 0; i < 16; i++) acc[i] = 0.f;
  for (int e = 0; e < 64; e++){
    float w = w_out[(size_t)(h * 64 + e) * 1024 + f] * inv_s[e];
#pragma unroll
    for (int dd = 0; dd < 16; dd++)
      acc[dd] += ctxs[(dg * 16 + dd) * 64 + e] * w;
  }
  unsigned short* op = ctx2t + ((size_t)b * 1024 + f) * 1024 + h * 64 + dg * 16;
#pragma unroll
  for (int g = 0; g < 4; g++){
    ushort4 o;
    o.x = f2bf(acc[g*4+0]); o.y = f2bf(acc[g*4+1]);
    o.z = f2bf(acc[g*4+2]); o.w = f2bf(acc[g*4+3]);
    *(ushort4*)&op[g*4] = o;
  }
}

extern "C" void kernel_launch(void* const* d_in, const int* in_sizes, int n_in,
                              void* d_out, int out_size, void* d_ws, size_t ws_size,
                              hipStream_t stream) {
  const float* x     = (const float*)d_in[0];  // [4,4096,1024]
  const float* w_qkv = (const float*)d_in[1];  // [1024,3072]
  const float* w_out = (const float*)d_in[2];  // [1024,1024]
  const float* b_out = (const float*)d_in[3];  // [1024]
  float* out = (float*)d_out;                  // [4,4096,1024] fp32

  const int M = 4 * SEQ;  // 16384

  unsigned short* xb = (unsigned short*)d_out;  // dead before gemm_final writes

  char* wp = (char*)d_ws;
  size_t off = 0;
  auto nxt = [&](size_t bytes) -> char* {
    char* p = wp + off;
    off += (bytes + 255) & ~(size_t)255;
    return p;
  };
  unsigned short* wqkvT = (unsigned short*)nxt((size_t)3072 * 1024 * 2);
  unsigned short* qt    = (unsigned short*)nxt((size_t)64 * 64 * SEQ * 2);
  unsigned short* kt    = (unsigned short*)nxt((size_t)64 * 64 * SEQ * 2);
  unsigned short* vb    = (unsigned short*)nxt((size_t)M * 1024 * 2);
  float*          ctxp  = (float*)wqkvT;       // aliases wqkvT (dead after qkv_gemm)
  unsigned short* ctx2t = qt;                  // aliases qt (dead after ctx_partial)

  // 1. converts
  cvt_f32_bf16<<<(M * 1024) / 4 / 256, 256, 0, stream>>>((const float4*)x, (ushort4*)xb);
  transpose_cvt<<<dim3(3072 / 64, 1024 / 64), 256, 0, stream>>>(w_qkv, wqkvT, 1024, 3072);

  // 2. fused qkv GEMM (256^2 tile, 4-deep pipeline) -> qt, kt, vb
  qkv_gemm<<<768, 512, 0, stream>>>(xb, wqkvT, qt, kt, vb);

  // 3. context partials (fp32), 256 blocks
  ctx_partial<<<64 * 4, 256, 0, stream>>>(qt, kt, ctxp);

  // 4. ctx2t[b][f][hd]
  ctx2_kernel<<<64 * 16, 256, 0, stream>>>(ctxp, w_out, ctx2t);

  // 5. final batched GEMM (256^2 tile, 4-deep pipeline)
  gemm_final<<<256, 512, 0, stream>>>(vb, ctx2t, out, b_out);
}